// Round 1
// baseline (1499.728 us; speedup 1.0000x reference)
//
#include <hip/hip_runtime.h>

#define N_NODES 100000
#define N_EDGES 1600000
#define DIM 64

// ---------------------------------------------------------------------------
// Kernel 1: agg[dst[e]] += x[src[e]]  (segment_sum via global f32 atomics)
// 16 threads per edge, each thread handles one float4 (4 atomics).
// x-row reads are coalesced (16 consecutive float4 per edge-group).
// ---------------------------------------------------------------------------
__global__ __launch_bounds__(256) void scatter_kernel(
    const float* __restrict__ x,
    const int* __restrict__ src,
    const int* __restrict__ dst,
    float* __restrict__ agg)
{
    long long tid = (long long)blockIdx.x * 256 + threadIdx.x;
    int e = (int)(tid >> 4);
    int q = (int)(tid & 15);
    if (e >= N_EDGES) return;
    int sI = src[e];
    int dI = dst[e];
    float4 v = ((const float4*)(x + (size_t)sI * DIM))[q];
    float* ar = agg + (size_t)dI * DIM + (size_t)q * 4;
    atomicAdd(ar + 0, v.x);
    atomicAdd(ar + 1, v.y);
    atomicAdd(ar + 2, v.z);
    atomicAdd(ar + 3, v.w);
}

// ---------------------------------------------------------------------------
// Kernel 2: per node i: r = relu((x_i + agg_i) @ W1 + b1);
//           s += w_i * r; sw += w_i      (accumulated into sout[0..64])
// One wave per 4 nodes per iteration; W1 staged in LDS (16 KB);
// v broadcast through LDS (wave-private rows, alias-ordered, no barrier).
// Lane j owns output column j; W1s[k*64+j] reads are 2-way bank (free).
// ---------------------------------------------------------------------------
__global__ __launch_bounds__(256) void mlp_kernel(
    const float* __restrict__ x,
    const float* __restrict__ agg,
    const float* __restrict__ weights,
    const float* __restrict__ W1,
    const float* __restrict__ b1,
    float* __restrict__ sout)
{
    __shared__ float W1s[DIM * DIM];      // 16 KB
    __shared__ float vbuf[4][4][DIM];     // 4 KB: [wave][node][k]
    __shared__ float sred[4][DIM];        // 1 KB

    const int tid  = threadIdx.x;
    const int lane = tid & 63;
    const int wave = tid >> 6;

    for (int i = tid; i < DIM * DIM; i += 256) W1s[i] = W1[i];
    __syncthreads();

    const float bias = b1[lane];
    float sacc  = 0.f;
    float swacc = 0.f;

    const int gwave   = blockIdx.x * 4 + wave;
    const int nw      = gridDim.x * 4;
    const int ngroups = N_NODES / 4;   // 25000, exact

    for (int g = gwave; g < ngroups; g += nw) {
        const int i0 = g * 4;
        const size_t base = (size_t)i0 * DIM + lane;
        float v0 = x[base + 0 * DIM] + agg[base + 0 * DIM];
        float v1 = x[base + 1 * DIM] + agg[base + 1 * DIM];
        float v2 = x[base + 2 * DIM] + agg[base + 2 * DIM];
        float v3 = x[base + 3 * DIM] + agg[base + 3 * DIM];
        vbuf[wave][0][lane] = v0;
        vbuf[wave][1][lane] = v1;
        vbuf[wave][2][lane] = v2;
        vbuf[wave][3][lane] = v3;
        // same-wave LDS write->read: ordered via alias analysis + lgkmcnt

        float a0 = bias, a1 = bias, a2 = bias, a3 = bias;
        #pragma unroll
        for (int k = 0; k < DIM; k += 4) {
            float4 q0 = *(const float4*)&vbuf[wave][0][k];  // broadcast reads
            float4 q1 = *(const float4*)&vbuf[wave][1][k];
            float4 q2 = *(const float4*)&vbuf[wave][2][k];
            float4 q3 = *(const float4*)&vbuf[wave][3][k];
            float w0 = W1s[(k + 0) * DIM + lane];
            float w1 = W1s[(k + 1) * DIM + lane];
            float w2 = W1s[(k + 2) * DIM + lane];
            float w3 = W1s[(k + 3) * DIM + lane];
            a0 = fmaf(q0.x, w0, a0); a0 = fmaf(q0.y, w1, a0);
            a0 = fmaf(q0.z, w2, a0); a0 = fmaf(q0.w, w3, a0);
            a1 = fmaf(q1.x, w0, a1); a1 = fmaf(q1.y, w1, a1);
            a1 = fmaf(q1.z, w2, a1); a1 = fmaf(q1.w, w3, a1);
            a2 = fmaf(q2.x, w0, a2); a2 = fmaf(q2.y, w1, a2);
            a2 = fmaf(q2.z, w2, a2); a2 = fmaf(q2.w, w3, a2);
            a3 = fmaf(q3.x, w0, a3); a3 = fmaf(q3.y, w1, a3);
            a3 = fmaf(q3.z, w2, a3); a3 = fmaf(q3.w, w3, a3);
        }

        const float wt0 = weights[i0 + 0];
        const float wt1 = weights[i0 + 1];
        const float wt2 = weights[i0 + 2];
        const float wt3 = weights[i0 + 3];
        sacc = fmaf(fmaxf(a0, 0.f), wt0, sacc);
        sacc = fmaf(fmaxf(a1, 0.f), wt1, sacc);
        sacc = fmaf(fmaxf(a2, 0.f), wt2, sacc);
        sacc = fmaf(fmaxf(a3, 0.f), wt3, sacc);
        if (lane == 0) swacc += wt0 + wt1 + wt2 + wt3;
    }

    sred[wave][lane] = sacc;
    __syncthreads();
    if (wave == 0) {
        float t = sred[0][lane] + sred[1][lane] + sred[2][lane] + sred[3][lane];
        atomicAdd(&sout[lane], t);
    }
    if (lane == 0) atomicAdd(&sout[DIM], swacc);
}

// ---------------------------------------------------------------------------
// Kernel 3: out[j] = sum_k s[k]*W2[k][j] + sw*b2[j]   (single tiny block)
// ---------------------------------------------------------------------------
__global__ void finalize_kernel(
    const float* __restrict__ sout,
    const float* __restrict__ W2,
    const float* __restrict__ b2,
    float* __restrict__ out)
{
    const int j = threadIdx.x;
    const float sw = sout[DIM];
    float acc = sw * b2[j];
    #pragma unroll
    for (int k = 0; k < DIM; ++k)
        acc = fmaf(sout[k], W2[k * DIM + j], acc);
    out[j] = acc;
}

extern "C" void kernel_launch(void* const* d_in, const int* in_sizes, int n_in,
                              void* d_out, int out_size, void* d_ws, size_t ws_size,
                              hipStream_t stream)
{
    const float* x       = (const float*)d_in[0];
    const int*   ei      = (const int*)d_in[1];   // [2, N_EDGES]: src row, dst row
    const float* weights = (const float*)d_in[2];
    const float* W1      = (const float*)d_in[3];
    const float* b1      = (const float*)d_in[4];
    const float* W2      = (const float*)d_in[5];
    const float* b2      = (const float*)d_in[6];
    float* out = (float*)d_out;

    float* agg  = (float*)d_ws;                       // [N_NODES, DIM]
    float* sout = agg + (size_t)N_NODES * DIM;        // [DIM+1]

    // zero agg + accumulators (ws is re-poisoned to 0xAA before every call)
    hipMemsetAsync(d_ws, 0, (size_t)N_NODES * DIM * sizeof(float) + (DIM + 1) * sizeof(float), stream);

    // scatter: 16 threads/edge
    const long long total_thr = (long long)N_EDGES * 16;
    const int nblk = (int)((total_thr + 255) / 256);
    scatter_kernel<<<nblk, 256, 0, stream>>>(x, ei, ei + N_EDGES, agg);

    mlp_kernel<<<800, 256, 0, stream>>>(x, agg, weights, W1, b1, sout);

    finalize_kernel<<<1, 64, 0, stream>>>(sout, W2, b2, out);
}

// Round 2
// 579.303 us; speedup vs baseline: 2.5888x; 2.5888x over previous
//
#include <hip/hip_runtime.h>

#define N_NODES 100000
#define N_EDGES 1600000
#define DIM 64
#define NB1 391           // ceil(N_NODES/256)

// ---------------- workspace layout (int units) ----------------
// counts    : [0,          100096)   (NB1*256, padded)
// soutF     : [100096,     100176)   (65 floats used; zeroed with counts)
// cursor    : [100176,     200272)
// offsets   : [200272,     300373)   (N_NODES+1)
// blocksums : [300416,     300928)   (512)
// csr       : [300928,     1900928)  (N_EDGES)
#define OFF_SOUT    100096
#define OFF_CURSOR  100176
#define OFF_OFFSETS 200272
#define OFF_BSUMS   300416
#define OFF_CSR     300928

// ---------------------------------------------------------------------------
// K1: histogram of dst
// ---------------------------------------------------------------------------
__global__ __launch_bounds__(256) void hist_kernel(
    const int* __restrict__ dst, int* __restrict__ counts)
{
    int e = blockIdx.x * 256 + threadIdx.x;
    if (e < N_EDGES) atomicAdd(&counts[dst[e]], 1);
}

// ---------------------------------------------------------------------------
// K2: per-block sums of counts
// ---------------------------------------------------------------------------
__global__ __launch_bounds__(256) void blocksum_kernel(
    const int* __restrict__ counts, int* __restrict__ bsums)
{
    __shared__ int s[256];
    int t = threadIdx.x;
    int idx = blockIdx.x * 256 + t;
    s[t] = (idx < N_NODES) ? counts[idx] : 0;
    __syncthreads();
    for (int d = 128; d > 0; d >>= 1) {
        if (t < d) s[t] += s[t + d];
        __syncthreads();
    }
    if (t == 0) bsums[blockIdx.x] = s[0];
}

// ---------------------------------------------------------------------------
// K3: exclusive scan of the 391 block sums (single block, in place)
// ---------------------------------------------------------------------------
__global__ __launch_bounds__(512) void scanblocks_kernel(int* __restrict__ bsums)
{
    __shared__ int s[512];
    int t = threadIdx.x;
    int v = (t < NB1) ? bsums[t] : 0;
    s[t] = v;
    __syncthreads();
    for (int d = 1; d < 512; d <<= 1) {
        int add = (t >= d) ? s[t - d] : 0;
        __syncthreads();
        s[t] += add;
        __syncthreads();
    }
    if (t < NB1) bsums[t] = (t == 0) ? 0 : s[t - 1];
}

// ---------------------------------------------------------------------------
// K4: per-block exclusive scan + block offset -> offsets[] and cursor[]
// ---------------------------------------------------------------------------
__global__ __launch_bounds__(256) void offsets_kernel(
    const int* __restrict__ counts, const int* __restrict__ bsums,
    int* __restrict__ offsets, int* __restrict__ cursor)
{
    __shared__ int s[256];
    int t = threadIdx.x;
    int idx = blockIdx.x * 256 + t;
    int c = (idx < N_NODES) ? counts[idx] : 0;
    s[t] = c;
    __syncthreads();
    for (int d = 1; d < 256; d <<= 1) {
        int add = (t >= d) ? s[t - d] : 0;
        __syncthreads();
        s[t] += add;
        __syncthreads();
    }
    int excl = (t == 0) ? 0 : s[t - 1];
    int off = bsums[blockIdx.x] + excl;
    if (idx < N_NODES) { offsets[idx] = off; cursor[idx] = off; }
    if (idx == 0) offsets[N_NODES] = N_EDGES;
}

// ---------------------------------------------------------------------------
// K5: scatter edge src indices into CSR slots
// ---------------------------------------------------------------------------
__global__ __launch_bounds__(256) void fill_kernel(
    const int* __restrict__ src, const int* __restrict__ dst,
    int* __restrict__ cursor, int* __restrict__ csr)
{
    int e = blockIdx.x * 256 + threadIdx.x;
    if (e < N_EDGES) {
        int d = dst[e];
        int pos = atomicAdd(&cursor[d], 1);
        csr[pos] = src[e];
    }
}

// ---------------------------------------------------------------------------
// K6: fused gather + layer-1 matvec + weighted reduction.
// Wave handles 4 nodes/iter. Lane j owns output column j.
// agg never materialized: x rows gathered straight from L2/L3.
// ---------------------------------------------------------------------------
__global__ __launch_bounds__(256) void gather_mlp_kernel(
    const float* __restrict__ x,
    const int* __restrict__ offsets,
    const int* __restrict__ csr,
    const float* __restrict__ weights,
    const float* __restrict__ W1,
    const float* __restrict__ b1,
    float* __restrict__ sout)
{
    __shared__ float W1s[DIM * DIM];      // 16 KB
    __shared__ float vbuf[4][4][DIM];     // 4 KB
    __shared__ float sred[4][DIM];        // 1 KB

    const int tid  = threadIdx.x;
    const int lane = tid & 63;
    const int wave = tid >> 6;

    for (int i = tid; i < DIM * DIM; i += 256) W1s[i] = W1[i];
    __syncthreads();

    const float bias = b1[lane];
    float sacc  = 0.f;
    float swacc = 0.f;

    const int gwave   = blockIdx.x * 4 + wave;
    const int nw      = gridDim.x * 4;
    const int ngroups = N_NODES / 4;   // 25000 exact

    for (int g = gwave; g < ngroups; g += nw) {
        const int i0 = g * 4;
        #pragma unroll
        for (int n = 0; n < 4; ++n) {
            const int node = i0 + n;
            float a = x[(size_t)node * DIM + lane];   // self term (eps=0)
            const int beg = offsets[node];
            const int end = offsets[node + 1];
            for (int j = beg; j < end; ++j) {
                const int s = csr[j];                 // wave-uniform broadcast
                a += x[(size_t)s * DIM + lane];       // coalesced 256B row
            }
            vbuf[wave][n][lane] = a;
        }

        float a0 = bias, a1 = bias, a2 = bias, a3 = bias;
        #pragma unroll
        for (int k = 0; k < DIM; k += 4) {
            float4 q0 = *(const float4*)&vbuf[wave][0][k];
            float4 q1 = *(const float4*)&vbuf[wave][1][k];
            float4 q2 = *(const float4*)&vbuf[wave][2][k];
            float4 q3 = *(const float4*)&vbuf[wave][3][k];
            float w0 = W1s[(k + 0) * DIM + lane];
            float w1 = W1s[(k + 1) * DIM + lane];
            float w2 = W1s[(k + 2) * DIM + lane];
            float w3 = W1s[(k + 3) * DIM + lane];
            a0 = fmaf(q0.x, w0, a0); a0 = fmaf(q0.y, w1, a0);
            a0 = fmaf(q0.z, w2, a0); a0 = fmaf(q0.w, w3, a0);
            a1 = fmaf(q1.x, w0, a1); a1 = fmaf(q1.y, w1, a1);
            a1 = fmaf(q1.z, w2, a1); a1 = fmaf(q1.w, w3, a1);
            a2 = fmaf(q2.x, w0, a2); a2 = fmaf(q2.y, w1, a2);
            a2 = fmaf(q2.z, w2, a2); a2 = fmaf(q2.w, w3, a2);
            a3 = fmaf(q3.x, w0, a3); a3 = fmaf(q3.y, w1, a3);
            a3 = fmaf(q3.z, w2, a3); a3 = fmaf(q3.w, w3, a3);
        }

        const float wt0 = weights[i0 + 0];
        const float wt1 = weights[i0 + 1];
        const float wt2 = weights[i0 + 2];
        const float wt3 = weights[i0 + 3];
        sacc = fmaf(fmaxf(a0, 0.f), wt0, sacc);
        sacc = fmaf(fmaxf(a1, 0.f), wt1, sacc);
        sacc = fmaf(fmaxf(a2, 0.f), wt2, sacc);
        sacc = fmaf(fmaxf(a3, 0.f), wt3, sacc);
        if (lane == 0) swacc += wt0 + wt1 + wt2 + wt3;
    }

    sred[wave][lane] = sacc;
    __syncthreads();
    if (wave == 0) {
        float t = sred[0][lane] + sred[1][lane] + sred[2][lane] + sred[3][lane];
        atomicAdd(&sout[lane], t);
    }
    if (lane == 0) atomicAdd(&sout[DIM], swacc);
}

// ---------------------------------------------------------------------------
// K7: out = s @ W2 + sw * b2
// ---------------------------------------------------------------------------
__global__ void finalize_kernel(
    const float* __restrict__ sout,
    const float* __restrict__ W2,
    const float* __restrict__ b2,
    float* __restrict__ out)
{
    const int j = threadIdx.x;
    const float sw = sout[DIM];
    float acc = sw * b2[j];
    #pragma unroll
    for (int k = 0; k < DIM; ++k)
        acc = fmaf(sout[k], W2[k * DIM + j], acc);
    out[j] = acc;
}

extern "C" void kernel_launch(void* const* d_in, const int* in_sizes, int n_in,
                              void* d_out, int out_size, void* d_ws, size_t ws_size,
                              hipStream_t stream)
{
    const float* x       = (const float*)d_in[0];
    const int*   ei      = (const int*)d_in[1];
    const float* weights = (const float*)d_in[2];
    const float* W1      = (const float*)d_in[3];
    const float* b1      = (const float*)d_in[4];
    const float* W2      = (const float*)d_in[5];
    const float* b2      = (const float*)d_in[6];
    float* out = (float*)d_out;

    const int* src = ei;
    const int* dst = ei + N_EDGES;

    int*   wsI     = (int*)d_ws;
    int*   counts  = wsI;
    float* soutF   = (float*)(wsI + OFF_SOUT);
    int*   cursor  = wsI + OFF_CURSOR;
    int*   offsets = wsI + OFF_OFFSETS;
    int*   bsums   = wsI + OFF_BSUMS;
    int*   csr     = wsI + OFF_CSR;

    // zero counts + sout in one shot (layout-contiguous)
    hipMemsetAsync(d_ws, 0, (size_t)(OFF_SOUT + 80) * sizeof(int), stream);

    const int eblk = (N_EDGES + 255) / 256;   // 6250
    hist_kernel      <<<eblk, 256, 0, stream>>>(dst, counts);
    blocksum_kernel  <<<NB1,  256, 0, stream>>>(counts, bsums);
    scanblocks_kernel<<<1,    512, 0, stream>>>(bsums);
    offsets_kernel   <<<NB1,  256, 0, stream>>>(counts, bsums, offsets, cursor);
    fill_kernel      <<<eblk, 256, 0, stream>>>(src, dst, cursor, csr);
    gather_mlp_kernel<<<800,  256, 0, stream>>>(x, offsets, csr, weights, W1, b1, soutF);
    finalize_kernel  <<<1,     64, 0, stream>>>(soutF, W2, b2, out);
}